// Round 7
// baseline (12724.327 us; speedup 1.0000x reference)
//
#include <hip/hip_runtime.h>
#include <hip/hip_bf16.h>

typedef unsigned short ushort_t;

#define FEAT 128
#define HF   512
#define NRBF 50
#define NNODE 10000
#define NEDGE 250000

__device__ __forceinline__ float b2f(unsigned int b){
    unsigned int u = (b & 0xffffu) << 16;
    float f; __builtin_memcpy(&f, &u, 4); return f;
}
__device__ __forceinline__ unsigned short f2b(float f){
    __hip_bfloat16 h = __float2bfloat16(f);
    unsigned short u; __builtin_memcpy(&u, &h, 2); return u;
}
__device__ __forceinline__ float silu_f(float x){ return x / (1.f + __expf(-x)); }

// fp32 inputs iff low 16 bits of ln_gamma[0] are zero (R4: fp32 branch confirmed on HW)
__device__ __forceinline__ bool is_fp32(const void* lng){
    return ((((const unsigned int*)lng)[0]) & 0xffffu) == 0u;
}
__device__ __forceinline__ float ld_f(const void* p, long idx, bool fp32){
    return fp32 ? ((const float*)p)[idx] : b2f(((const ushort_t*)p)[idx]);
}
__device__ __forceinline__ ushort_t ld_bf(const void* p, long idx, bool fp32){
    return fp32 ? f2b(((const float*)p)[idx]) : ((const ushort_t*)p)[idx];
}

// ---------------- sentinel (ws too small diagnostic; should never fire) ----------------
__global__ __launch_bounds__(256) void k_sentinel(float* __restrict__ out){
    int x = blockIdx.x*256 + threadIdx.x;
    if (x < NNODE*FEAT*4) out[x] = 1.0f;
}

// ---------------- normalize nbrs (int32 or int64) -> clamped int32 ----------------
__global__ __launch_bounds__(256) void k_nbrs(const unsigned int* __restrict__ raw, int* __restrict__ out){
    int x = blockIdx.x*256 + threadIdx.x;
    if (x >= 2*NEDGE) return;
    unsigned int m = raw[1]|raw[3]|raw[5]|raw[7]|raw[9]|raw[11]|raw[13]|raw[15];
    int v = (m == 0u) ? (int)raw[2*x] : (int)raw[x];
    out[x] = ((unsigned)v < (unsigned)NNODE) ? v : 0;
}

// ---------------- convert all weights/biases -> bf16 block (ORIGINAL layouts) ----------
// wb element offsets: Wq@0[128][512] Wk@65536 Wv@131072 Wdk@196608[50][512] Wdv@222208
//                     Wd@247808[512][384] cb@444416: ln_g(128) ln_b(128) bq(512) bk(512)
//                     bv(512) bdk(512) bdv(512) bd(384)  => total 447616
#define WB_TOTAL 447616
#define CB_OFF   444416
__global__ __launch_bounds__(256) void k_wconv(
    const void* Wq, const void* Wk, const void* Wv,
    const void* Wdk, const void* Wdv, const void* Wd,
    const void* lng, const void* lnb, const void* bq, const void* bk, const void* bv,
    const void* bdk, const void* bdv, const void* bd,
    ushort_t* __restrict__ wb)
{
    int idx = blockIdx.x*256 + threadIdx.x;
    if (idx >= WB_TOTAL) return;
    const bool fp32 = is_fp32(lng);
    const void* srcs[14] = {Wq,Wk,Wv,Wdk,Wdv,Wd,lng,lnb,bq,bk,bv,bdk,bdv,bd};
    const int sizes[14] = {65536,65536,65536,25600,25600,196608,128,128,512,512,512,512,512,384};
    int s = 0, off = idx;
    while (off >= sizes[s]){ off -= sizes[s]; s++; }
    wb[idx] = ld_bf(srcs[s], off, fp32);
}

// ---------------- K1: LayerNorm + QKV (scalar fp32 math, 8 nodes/block) ----------------
__global__ __launch_bounds__(256) void k_qkv_s(
    const void* __restrict__ s_j, const void* __restrict__ lng, const ushort_t* __restrict__ wb,
    ushort_t* __restrict__ q, ushort_t* __restrict__ k, ushort_t* __restrict__ v)
{
    __shared__ float x[8][132];
    const int t = threadIdx.x;
    const bool fp32 = is_fp32(lng);
    const int g = t >> 5, l = t & 31;
    const long node = (long)blockIdx.x*8 + g;
    const ushort_t* cb = wb + CB_OFF;

    float v0 = ld_f(s_j, node*FEAT + l,      fp32);
    float v1 = ld_f(s_j, node*FEAT + 32 + l, fp32);
    float v2 = ld_f(s_j, node*FEAT + 64 + l, fp32);
    float v3 = ld_f(s_j, node*FEAT + 96 + l, fp32);
    float s  = v0+v1+v2+v3, ss = v0*v0+v1*v1+v2*v2+v3*v3;
    #pragma unroll
    for (int off=16; off; off>>=1){ s += __shfl_xor(s, off, 32); ss += __shfl_xor(ss, off, 32); }
    float mu = s*(1.f/FEAT);
    float var = ss*(1.f/FEAT) - mu*mu;    // population variance (jnp.var)
    float sc = rsqrtf(var + 1e-5f);
    x[g][l]      = (v0-mu)*sc*b2f(cb[l])      + b2f(cb[128+l]);
    x[g][32+l]   = (v1-mu)*sc*b2f(cb[32+l])   + b2f(cb[160+l]);
    x[g][64+l]   = (v2-mu)*sc*b2f(cb[64+l])   + b2f(cb[192+l]);
    x[g][96+l]   = (v3-mu)*sc*b2f(cb[96+l])   + b2f(cb[224+l]);
    __syncthreads();

    for (int c=0; c<48; c++){
        int og = l + c*32;
        int mat = og >> 9, o = og & 511;
        const ushort_t* W = wb + mat*65536;
        float a = b2f(cb[256 + mat*512 + o]);
        #pragma unroll 4
        for (int f=0; f<FEAT; f++) a += x[g][f] * b2f(W[f*HF + o]);
        ushort_t* outp = (mat==0)?q:((mat==1)?k:v);
        outp[node*HF + o] = f2b(a);
    }
}

// ---------------- K2: fused edge kernel, scalar fp32, 8 edges/block ----------------
#define EPB 8
struct __align__(16) ESmem {
    float rbf[EPB][52];
    union {
        float dk[EPB][512];
        float outv[EPB][388];
    };
    float dv[EPB][512];
    float msg[EPB][512];
    float attn[EPB][4];
    float unit[EPB][3];
    float dist[EPB];
    int   ei[EPB], ej[EPB];
};

__global__ __launch_bounds__(256) void k_edge_s(
    const void* __restrict__ r_ij, const void* __restrict__ lng, const int* __restrict__ nb,
    const ushort_t* __restrict__ q, const ushort_t* __restrict__ k, const ushort_t* __restrict__ v,
    const void* __restrict__ v_j, const ushort_t* __restrict__ wb,
    float* __restrict__ acc_s, float* __restrict__ acc_v)
{
    __shared__ ESmem sm;
    const int t = threadIdx.x;
    const long e0 = (long)blockIdx.x * EPB;
    const bool fp32 = is_fp32(lng);
    const ushort_t* cb = wb + CB_OFF;

    // P1: dist/unit/indices  (SPEC orientation: col0 = i_dst, col1 = j_src)
    if (t < EPB){
        float rx = ld_f(r_ij, (e0+t)*3+0, fp32);
        float ry = ld_f(r_ij, (e0+t)*3+1, fp32);
        float rz = ld_f(r_ij, (e0+t)*3+2, fp32);
        float d = sqrtf(rx*rx + ry*ry + rz*rz + 3e-15f);
        sm.dist[t] = d;
        float inv = 1.f/d;
        sm.unit[t][0]=rx*inv; sm.unit[t][1]=ry*inv; sm.unit[t][2]=rz*inv;
        sm.ei[t] = nb[(e0+t)*2+0];
        sm.ej[t] = nb[(e0+t)*2+1];
    }
    __syncthreads();

    // P2: rbf fp32
    for (int idx=t; idx<EPB*NRBF; idx+=256){
        int e = idx/NRBF, m = idx%NRBF;
        const float WIDTH = 5.f/49.f;
        const float GAMMA = 0.5f/(WIDTH*WIDTH);
        float dm = sm.dist[e] - (float)m*WIDTH;
        sm.rbf[e][m] = __expf(-GAMMA*dm*dm);
    }
    __syncthreads();

    // P3: dk/dv = silu(rbf @ Wdk/Wdv + b)
    {
        int e = t>>5, l = t&31;
        for (int c=0; c<32; c++){
            int og = l + c*32;
            int mat = og >> 9, o = og & 511;
            const ushort_t* W = wb + (mat ? 222208 : 196608);
            float a = b2f(cb[1792 + mat*512 + o]);
            #pragma unroll 5
            for (int m=0; m<NRBF; m++) a += sm.rbf[e][m] * b2f(W[m*HF + o]);
            float sv = silu_f(a);
            if (mat) sm.dv[e][o] = sv; else sm.dk[e][o] = sv;
        }
    }
    __syncthreads();

    // P4: attn[e][h] = silu(sum_f q[i,h,f]*k[j,h,f]*dk[e,h,f])
    {
        int pair = t>>3, sub = t&7;
        int e = pair>>2, h = pair&3;
        long i = sm.ei[e], j = sm.ej[e];
        float p = 0.f;
        for (int f=sub; f<FEAT; f+=8){
            int o = h*FEAT + f;
            p += b2f(q[i*HF+o]) * b2f(k[j*HF+o]) * sm.dk[e][o];
        }
        #pragma unroll
        for (int off=4; off; off>>=1) p += __shfl_xor(p, off, 8);
        if (sub == 0) sm.attn[e][h] = silu_f(p);
    }
    __syncthreads();

    // P5: msg[e][f] = v[j,f]*dv[e,f]*attn[e][f/128]
    for (int c=0; c<16; c++){
        int idx = c*256 + t; int e = idx>>9, o = idx&511;
        long j = sm.ej[e];
        sm.msg[e][o] = b2f(v[j*HF+o]) * sm.dv[e][o] * sm.attn[e][o>>7];
    }
    __syncthreads();

    // P6: out = msg @ Wd + bd (overlays dk)
    {
        int e = t>>5, l = t&31;
        const ushort_t* Wd_ = wb + 247808;
        for (int c=0; c<12; c++){
            int o = l + c*32;
            float a = b2f(cb[2816 + o]);
            #pragma unroll 4
            for (int f=0; f<HF; f++) a += sm.msg[e][f] * b2f(Wd_[f*384 + o]);
            sm.outv[e][o] = a;
        }
    }
    __syncthreads();

    // P7: scatter
    for (int c=0; c<4; c++){
        int idx = c*256 + t; int e = idx>>7, f = idx&127;
        long i = sm.ei[e], j = sm.ej[e];
        float o0v = sm.outv[e][f];
        float o1v = sm.outv[e][128+f];
        float o2v = sm.outv[e][256+f];
        long vb = (j*FEAT + f)*3;
        float vj0 = ld_f(v_j, vb+0, fp32);
        float vj1 = ld_f(v_j, vb+1, fp32);
        float vj2 = ld_f(v_j, vb+2, fp32);
        atomicAdd(&acc_s[i*FEAT + f], o1v);
        float* av = acc_v + (i*FEAT + f)*3;
        atomicAdd(av+0, o2v*sm.unit[e][0] + o0v*vj0);
        atomicAdd(av+1, o2v*sm.unit[e][1] + o0v*vj1);
        atomicAdd(av+2, o2v*sm.unit[e][2] + o0v*vj2);
    }
}

// ---------------- fp32 accumulators -> FP32 output (d_out is float*, R6 finding) ------
__global__ __launch_bounds__(256) void k_out(const float* __restrict__ acc, float* __restrict__ out){
    int idx = blockIdx.x*256 + threadIdx.x;
    out[idx] = acc[idx];
}

extern "C" void kernel_launch(void* const* d_in, const int* in_sizes, int n_in,
                              void* d_out, int out_size, void* d_ws, size_t ws_size,
                              hipStream_t stream)
{
    const void* s_j  = d_in[0];
    const void* v_j  = d_in[1];
    const void* r_ij = d_in[2];
    const unsigned int* nbrs_raw = (const unsigned int*)d_in[3];
    const void* ln_g = d_in[4];
    const void* ln_b = d_in[5];
    const void* Wq = d_in[6];   const void* bq  = d_in[7];
    const void* Wk = d_in[8];   const void* bk  = d_in[9];
    const void* Wv = d_in[10];  const void* bv  = d_in[11];
    const void* Wdk= d_in[12];  const void* bdk = d_in[13];
    const void* Wdv= d_in[14];  const void* bdv = d_in[15];
    const void* Wd = d_in[16];  const void* bd  = d_in[17];

    // ws layout (bytes):
    //   acc  : 0          .. 20,480,000   (5.12M fp32: acc_s | acc_v)
    //   kk   : 20,480,000 .. 30,720,000   (bf16)
    //   vv   : 30,720,000 .. 40,960,000   (bf16)
    //   wb   : 40,960,000 .. 41,855,232   (447,616 bf16)
    //   nb32 : 41,855,232 .. 43,855,232
    // NEED = 43,855,232  (< 43,883,904 proven lower bound on ws_size from R3)
    const size_t NEED = 43855232;
    if (ws_size < NEED){
        k_sentinel<<<20000, 256, 0, stream>>>((float*)d_out);
        return;
    }

    char* ws = (char*)d_ws;
    float*    acc  = (float*)(ws);
    ushort_t* q    = (ushort_t*)d_out;     // bf16 staging in the fp32 d_out (20.48MB); k_out overwrites last
    ushort_t* kk   = (ushort_t*)(ws + 20480000);
    ushort_t* vv   = (ushort_t*)(ws + 30720000);
    ushort_t* wb   = (ushort_t*)(ws + 40960000);
    int*      nb32 = (int*)(ws + 41855232);

    hipMemsetAsync(acc, 0, 20480000, stream);
    k_nbrs <<<1954, 256, 0, stream>>>(nbrs_raw, nb32);
    k_wconv<<<1749, 256, 0, stream>>>(Wq,Wk,Wv,Wdk,Wdv,Wd, ln_g,ln_b,bq,bk,bv,bdk,bdv,bd, wb);
    k_qkv_s<<<1250, 256, 0, stream>>>(s_j, ln_g, wb, q, kk, vv);
    k_edge_s<<<31250, 256, 0, stream>>>(r_ij, ln_g, nb32, q, kk, vv, v_j, wb,
                                        acc, acc + 1280000);
    k_out  <<<20000, 256, 0, stream>>>(acc, (float*)d_out);
}

// Round 8
// 1499.033 us; speedup vs baseline: 8.4884x; 8.4884x over previous
//
#include <hip/hip_runtime.h>
#include <hip/hip_bf16.h>

typedef unsigned short ushort_t;
typedef short short8 __attribute__((ext_vector_type(8)));
typedef float floatx4 __attribute__((ext_vector_type(4)));

#define FEAT 128
#define HF   512
#define NRBF 50
#define NNODE 10000
#define NEDGE 250000

__device__ __forceinline__ float b2f(unsigned int b){
    unsigned int u = (b & 0xffffu) << 16;
    float f; __builtin_memcpy(&f, &u, 4); return f;
}
__device__ __forceinline__ unsigned short f2b(float f){
    __hip_bfloat16 h = __float2bfloat16(f);
    unsigned short u; __builtin_memcpy(&u, &h, 2); return u;
}
__device__ __forceinline__ float silu_f(float x){ return x / (1.f + __expf(-x)); }

// fp32 inputs iff low 16 bits of ln_gamma[0] are zero (R4/R7: fp32 confirmed on HW)
__device__ __forceinline__ bool is_fp32(const void* lng){
    return ((((const unsigned int*)lng)[0]) & 0xffffu) == 0u;
}
__device__ __forceinline__ float ld_f(const void* p, long idx, bool fp32){
    return fp32 ? ((const float*)p)[idx] : b2f(((const ushort_t*)p)[idx]);
}
__device__ __forceinline__ ushort_t ld_bf(const void* p, long idx, bool fp32){
    return fp32 ? f2b(((const float*)p)[idx]) : ((const ushort_t*)p)[idx];
}

// ---------------- sentinel (ws too small; should never fire: ws >= 43,883,904 proven) --
__global__ __launch_bounds__(256) void k_sentinel(float* __restrict__ out){
    int x = blockIdx.x*256 + threadIdx.x;
    if (x < NNODE*FEAT*4) out[x] = 1.0f;
}

// ---------------- normalize nbrs (int32 or int64) -> clamped int32 ----------------
__global__ __launch_bounds__(256) void k_nbrs(const unsigned int* __restrict__ raw, int* __restrict__ out){
    int x = blockIdx.x*256 + threadIdx.x;
    if (x >= 2*NEDGE) return;
    unsigned int m = raw[1]|raw[3]|raw[5]|raw[7]|raw[9]|raw[11]|raw[13]|raw[15];
    int v = (m == 0u) ? (int)raw[2*x] : (int)raw[x];
    out[x] = ((unsigned)v < (unsigned)NNODE) ? v : 0;
}

// ---------------- canonicalize ln/biases -> bf16 block ----------------
// cb (ushort elems): ln_g@0(128) ln_b@128(128) bq@256(512) bk@768(512)
//                    bv@1280(512) bdk@1792(512) bdv@2304(512) bd@2816(384)
__global__ __launch_bounds__(256) void k_conv(
    const void* ln_g, const void* ln_b, const void* bq, const void* bk, const void* bv,
    const void* bdk, const void* bdv, const void* bd, ushort_t* __restrict__ cb)
{
    const int t = threadIdx.x;
    const bool fp32 = is_fp32(ln_g);
    const void* srcs[8] = {ln_g, ln_b, bq, bk, bv, bdk, bdv, bd};
    const int offs[9] = {0,128,256,768,1280,1792,2304,2816,3200};
    for (int s=0; s<8; s++){
        int cnt = offs[s+1]-offs[s];
        for (int x=t; x<cnt; x+=256) cb[offs[s]+x] = ld_bf(srcs[s], x, fp32);
    }
}

// ---------------- weight transposes into B-fragment layouts (dtype-adaptive) ----------
// WqT/WkT/WvT: [512][128]; WdkT/WdvT: [512][64] (k zero-padded 50..63); WdT: [384][512]
__global__ __launch_bounds__(256) void k_prep(
    const void* __restrict__ Wq, const void* __restrict__ Wk, const void* __restrict__ Wv,
    const void* __restrict__ Wdk, const void* __restrict__ Wdv, const void* __restrict__ Wd,
    const void* __restrict__ lng,
    ushort_t* __restrict__ WqT, ushort_t* __restrict__ WkT, ushort_t* __restrict__ WvT,
    ushort_t* __restrict__ WdkT, ushort_t* __restrict__ WdvT, ushort_t* __restrict__ WdT)
{
    const bool fp32 = is_fp32(lng);
    int idx = blockIdx.x*256 + threadIdx.x;
    if (idx < 3*65536){
        int mat = idx >> 16; int o = idx & 65535;
        int c = o >> 7, r = o & 127;
        const void* src = (mat==0)?Wq:((mat==1)?Wk:Wv);
        ushort_t* dst = (mat==0)?WqT:((mat==1)?WkT:WvT);
        dst[o] = ld_bf(src, r*HF + c, fp32);
    } else if (idx < 3*65536 + 2*32768){
        int o2 = idx - 3*65536; int mat = o2 >> 15; int o = o2 & 32767;
        int c = o >> 6, kk = o & 63;
        const void* src = mat ? Wdv : Wdk;
        ushort_t* dst = mat ? WdvT : WdkT;
        dst[o] = (kk < NRBF) ? ld_bf(src, kk*HF + c, fp32) : (ushort_t)0;
    } else {
        int o = idx - (3*65536 + 2*32768);
        int c = o >> 9, kk = o & 511;
        WdT[o] = ld_bf(Wd, kk*384 + c, fp32);
    }
}

// ---------------- K1: LayerNorm + QKV projections (MFMA, 16 nodes/block) --------------
__global__ __launch_bounds__(256) void k_qkv2(
    const void* __restrict__ s_j, const void* __restrict__ lng, const ushort_t* __restrict__ cb,
    const ushort_t* __restrict__ WqT, const ushort_t* __restrict__ WkT, const ushort_t* __restrict__ WvT,
    ushort_t* __restrict__ q, ushort_t* __restrict__ k, ushort_t* __restrict__ v)
{
    __shared__ __align__(16) ushort_t xlds[16][136];   // row stride 272B = 17*16
    const int t = threadIdx.x;
    const int n = t >> 4, g = t & 15;
    const long node = (long)blockIdx.x*16 + n;
    const bool fp32 = is_fp32(lng);

    float xs[8];
    if (fp32){
        const float* sf = (const float*)s_j + node*FEAT + g*8;
        #pragma unroll
        for (int i=0;i<8;i++) xs[i] = sf[i];
    } else {
        short8 sv = *reinterpret_cast<const short8*>((const ushort_t*)s_j + node*FEAT + g*8);
        #pragma unroll
        for (int i=0;i<8;i++) xs[i] = b2f((unsigned short)sv[i]);
    }
    float sum = 0.f, ss = 0.f;
    #pragma unroll
    for (int i=0;i<8;i++){ sum += xs[i]; ss += xs[i]*xs[i]; }
    #pragma unroll
    for (int off=8; off; off>>=1){ sum += __shfl_xor(sum, off, 16); ss += __shfl_xor(ss, off, 16); }
    float mu = sum * (1.f/FEAT);
    float var = ss * (1.f/FEAT) - mu*mu;       // population var (jnp.var)
    float sc = rsqrtf(var + 1e-5f);
    short8 gv  = *reinterpret_cast<const short8*>(cb + g*8);        // ln_g
    short8 bv2 = *reinterpret_cast<const short8*>(cb + 128 + g*8);  // ln_b
    short8 xv;
    #pragma unroll
    for (int i=0;i<8;i++){
        float val = (xs[i]-mu)*sc*b2f((unsigned short)gv[i]) + b2f((unsigned short)bv2[i]);
        xv[i] = (short)f2b(val);
    }
    *reinterpret_cast<short8*>(&xlds[n][g*8]) = xv;
    __syncthreads();

    const int lane = t & 63, w = t >> 6;
    const int col = lane & 15, quad = lane >> 4;
    short8 a[4];   // A[m=lane&15][k=quad*8+j]
    #pragma unroll
    for (int ks=0; ks<4; ks++)
        a[ks] = *reinterpret_cast<const short8*>(&xlds[col][ks*32 + quad*8]);

    for (int ii=0; ii<24; ii++){
        int nt = w + ii*4;                  // 0..95 over 4 waves
        int mat = nt >> 5, o0 = (nt & 31) << 4;
        const ushort_t* WT  = (mat==0)?WqT:((mat==1)?WkT:WvT);
        const ushort_t* bia = cb + 256 + mat*512;
        ushort_t* outp      = (mat==0)?q:((mat==1)?k:v);
        floatx4 acc = {0.f,0.f,0.f,0.f};
        #pragma unroll
        for (int ks=0; ks<4; ks++){
            short8 b = *reinterpret_cast<const short8*>(WT + (o0+col)*FEAT + ks*32 + quad*8);
            acc = __builtin_amdgcn_mfma_f32_16x16x32_bf16(a[ks], b, acc, 0, 0, 0);
        }
        float bc = b2f(bia[o0+col]);
        #pragma unroll
        for (int reg=0; reg<4; reg++){
            int row = quad*4 + reg;         // C/D: row=quad*4+reg, col=lane&15
            outp[((long)blockIdx.x*16 + row)*HF + o0 + col] = f2b(acc[reg] + bc);
        }
    }
}

// ---------------- K2: fused edge kernel (MFMA), 16 edges/block ------------------------
struct __align__(16) EdgeSmem {
    int   i[16];
    int   jv[16];
    float unit[16][3];
    float dist[16];
    float attn[16][4];
    ushort_t rbf[16][72];           // row stride 144B
    union {
        ushort_t dkdv[2][16][520];  // row stride 1040B; dead after P4
        float    outb[16*385];      // overlay for P5/P6
    };
    ushort_t msg[16][520];          // row stride 1040B
};

__global__ __launch_bounds__(256) void k_edge(
    const void* __restrict__ r_ij, const void* __restrict__ lng, const int* __restrict__ nbrs32,
    const ushort_t* __restrict__ q, const ushort_t* __restrict__ k, const ushort_t* __restrict__ v,
    const void* __restrict__ v_j,
    const ushort_t* __restrict__ WdkT, const ushort_t* __restrict__ WdvT,
    const ushort_t* __restrict__ cb,
    const ushort_t* __restrict__ WdT,
    float* __restrict__ acc_s, float* __restrict__ acc_v)
{
    __shared__ EdgeSmem sm;

    const int t = threadIdx.x;
    const long e0 = (long)blockIdx.x * 16;
    const bool fp32 = is_fp32(lng);

    // P1: dist / unit / indices (spec orientation: col0 = i_dst, col1 = j_src)
    if (t < 16){
        int e = t;
        float rx = ld_f(r_ij, (e0+e)*3+0, fp32);
        float ry = ld_f(r_ij, (e0+e)*3+1, fp32);
        float rz = ld_f(r_ij, (e0+e)*3+2, fp32);
        float d = sqrtf(rx*rx + ry*ry + rz*rz + 3e-15f);
        sm.dist[e] = d;
        float inv = 1.f/d;
        sm.unit[e][0] = rx*inv; sm.unit[e][1] = ry*inv; sm.unit[e][2] = rz*inv;
        sm.i[e]  = nbrs32[(e0+e)*2+0];
        sm.jv[e] = nbrs32[(e0+e)*2+1];
    }
    __syncthreads();
    // P1b: rbf (bf16, zero-padded to k=64)
    {
        const float WIDTH = 5.f/49.f;
        const float GAMMA = 0.5f/(WIDTH*WIDTH);
        int e = t & 15, m0 = t >> 4;
        float d = sm.dist[e];
        for (int m = m0; m < 64; m += 16){
            float val = 0.f;
            if (m < NRBF){ float dm = d - (float)m*WIDTH; val = __expf(-GAMMA*dm*dm); }
            sm.rbf[e][m] = f2b(val);
        }
    }
    __syncthreads();

    const int lane = t & 63, w = t >> 6;
    const int col = lane & 15, quad = lane >> 4;

    // P2: dk/dv = silu(rbf @ Wdk/Wdv + b) via MFMA (K=64 -> 2 steps)
    {
        short8 a0 = *reinterpret_cast<const short8*>(&sm.rbf[col][quad*8]);
        short8 a1 = *reinterpret_cast<const short8*>(&sm.rbf[col][32 + quad*8]);
        for (int ii=0; ii<16; ii++){
            int nt = w + ii*4;                 // 0..63
            int mat = nt >> 5, o0 = (nt & 31) << 4;
            const ushort_t* WT  = mat ? WdvT : WdkT;
            const ushort_t* bia = cb + 1792 + mat*512;   // bdk / bdv
            floatx4 acc = {0.f,0.f,0.f,0.f};
            short8 b0 = *reinterpret_cast<const short8*>(WT + (o0+col)*64 + quad*8);
            acc = __builtin_amdgcn_mfma_f32_16x16x32_bf16(a0, b0, acc, 0, 0, 0);
            short8 b1 = *reinterpret_cast<const short8*>(WT + (o0+col)*64 + 32 + quad*8);
            acc = __builtin_amdgcn_mfma_f32_16x16x32_bf16(a1, b1, acc, 0, 0, 0);
            float bc = b2f(bia[o0+col]);
            #pragma unroll
            for (int reg=0; reg<4; reg++){
                int row = quad*4 + reg;        // edge index
                sm.dkdv[mat][row][o0+col] = f2b(silu_f(acc[reg] + bc));
            }
        }
    }
    __syncthreads();

    // P3: attn[e][h] = silu( sum_f q[i,h,f]*k[j,h,f]*dk[e,h,f] ); wave w = head w
    {
        int f = w*128 + 2*lane;
        for (int e=0; e<16; e++){
            long i = sm.i[e], jj = sm.jv[e];
            unsigned int qb = *reinterpret_cast<const unsigned int*>(q + i*HF + f);
            unsigned int kb = *reinterpret_cast<const unsigned int*>(k + jj*HF + f);
            unsigned int db = *reinterpret_cast<const unsigned int*>(&sm.dkdv[0][e][f]);
            float p = b2f(qb)*b2f(kb)*b2f(db) + b2f(qb>>16)*b2f(kb>>16)*b2f(db>>16);
            #pragma unroll
            for (int off=32; off; off>>=1) p += __shfl_xor(p, off, 64);
            if (lane == 0) sm.attn[e][w] = silu_f(p);
        }
    }
    __syncthreads();

    // P4: msg[e][f] = v[j,f] * dv[e,f] * attn[e][f/128]
    {
        int f = 2*t;
        int h = t >> 6;
        for (int e=0; e<16; e++){
            long jj = sm.jv[e];
            float at = sm.attn[e][h];
            unsigned int vb = *reinterpret_cast<const unsigned int*>(v + jj*HF + f);
            unsigned int db = *reinterpret_cast<const unsigned int*>(&sm.dkdv[1][e][f]);
            float m0v = b2f(vb)*b2f(db)*at;
            float m1v = b2f(vb>>16)*b2f(db>>16)*at;
            unsigned int o = (unsigned int)f2b(m0v) | ((unsigned int)f2b(m1v) << 16);
            *reinterpret_cast<unsigned int*>(&sm.msg[e][f]) = o;
        }
    }
    __syncthreads();

    // P5: out = msg(16x512) @ Wd(512x384) + bd via MFMA; out overlays dk/dv (dead)
    {
        floatx4 acc[6];
        #pragma unroll
        for (int ii=0; ii<6; ii++) acc[ii] = (floatx4){0.f,0.f,0.f,0.f};
        for (int ks=0; ks<16; ks++){
            short8 a = *reinterpret_cast<const short8*>(&sm.msg[col][ks*32 + quad*8]);
            #pragma unroll
            for (int ii=0; ii<6; ii++){
                int o0 = (w + ii*4) << 4;      // 24 N-tiles over 4 waves
                short8 b = *reinterpret_cast<const short8*>(WdT + (o0+col)*HF + ks*32 + quad*8);
                acc[ii] = __builtin_amdgcn_mfma_f32_16x16x32_bf16(a, b, acc[ii], 0, 0, 0);
            }
        }
        #pragma unroll
        for (int ii=0; ii<6; ii++){
            int o0 = (w + ii*4) << 4;
            float bc = b2f(cb[2816 + o0 + col]);   // bd
            #pragma unroll
            for (int reg=0; reg<4; reg++){
                int row = quad*4 + reg;
                sm.outb[row*385 + o0 + col] = acc[ii][reg] + bc;
            }
        }
    }
    __syncthreads();

    // P6: scatter: delta_s += out1; delta_v += out2*unit + out0*v_j[j]
    {
        int f = t & 127, half = t >> 7;
        for (int e = half*8; e < half*8 + 8; e++){
            long i = sm.i[e], jj = sm.jv[e];
            float o0v = sm.outb[e*385 + f];
            float o1v = sm.outb[e*385 + 128 + f];
            float o2v = sm.outb[e*385 + 256 + f];
            float ux = sm.unit[e][0], uy = sm.unit[e][1], uz = sm.unit[e][2];
            long base = (jj*FEAT + f)*3;
            float vj0 = ld_f(v_j, base+0, fp32);
            float vj1 = ld_f(v_j, base+1, fp32);
            float vj2 = ld_f(v_j, base+2, fp32);
            atomicAdd(&acc_s[i*FEAT + f], o1v);
            float* av = acc_v + (i*FEAT + f)*3;
            atomicAdd(av+0, o2v*ux + o0v*vj0);
            atomicAdd(av+1, o2v*uy + o0v*vj1);
            atomicAdd(av+2, o2v*uz + o0v*vj2);
        }
    }
}

// ---------------- fp32 accumulators -> fp32 output ----------------
__global__ __launch_bounds__(256) void k_out(const float* __restrict__ acc, float* __restrict__ out){
    int idx = blockIdx.x*256 + threadIdx.x;
    out[idx] = acc[idx];
}

extern "C" void kernel_launch(void* const* d_in, const int* in_sizes, int n_in,
                              void* d_out, int out_size, void* d_ws, size_t ws_size,
                              hipStream_t stream)
{
    const void* s_j  = d_in[0];
    const void* v_j  = d_in[1];
    const void* r_ij = d_in[2];
    const unsigned int* nbrs_raw = (const unsigned int*)d_in[3];
    const void* ln_g = d_in[4];
    const void* ln_b = d_in[5];
    const void* Wq = d_in[6];   const void* bq  = d_in[7];
    const void* Wk = d_in[8];   const void* bk  = d_in[9];
    const void* Wv = d_in[10];  const void* bv  = d_in[11];
    const void* Wdk= d_in[12];  const void* bdk = d_in[13];
    const void* Wdv= d_in[14];  const void* bdv = d_in[15];
    const void* Wd = d_in[16];  const void* bd  = d_in[17];

    // ws layout (bytes):
    //   acc    : 0          .. 20,480,000   (5.12M fp32: acc_s | acc_v)
    //   kk     : 20,480,000 ; vv : 30,720,000  (bf16)
    //   WqT    : 40,960,000 (+131072) ; WkT ; WvT
    //   WdkT   : 41,353,216 (+65536) ; WdvT (+65536)
    //   WdT    : 41,484,288 (+393216)
    //   nbrs32 : 41,877,504 (+2,000,000)
    //   cb     : 43,877,504 (+6,400)  => NEED = 43,883,904 (proven OK: R4 ran at this size)
    const size_t NEED = 43883904;
    if (ws_size < NEED){
        k_sentinel<<<20000, 256, 0, stream>>>((float*)d_out);
        return;
    }

    char* ws = (char*)d_ws;
    float*    acc  = (float*)(ws);
    ushort_t* q    = (ushort_t*)d_out;     // bf16 staging in fp32 d_out (first 10.24MB of 20.48MB)
    ushort_t* kk   = (ushort_t*)(ws + 20480000);
    ushort_t* vv   = (ushort_t*)(ws + 30720000);
    ushort_t* WqT  = (ushort_t*)(ws + 40960000);
    ushort_t* WkT  = (ushort_t*)(ws + 41091072);
    ushort_t* WvT  = (ushort_t*)(ws + 41222144);
    ushort_t* WdkT = (ushort_t*)(ws + 41353216);
    ushort_t* WdvT = (ushort_t*)(ws + 41418752);
    ushort_t* WdT  = (ushort_t*)(ws + 41484288);
    int*      nb32 = (int*)(ws + 41877504);
    ushort_t* cb   = (ushort_t*)(ws + 43877504);

    hipMemsetAsync(acc, 0, 20480000, stream);
    k_nbrs<<<1954, 256, 0, stream>>>(nbrs_raw, nb32);
    k_conv<<<1, 256, 0, stream>>>(ln_g, ln_b, bq, bk, bv, bdk, bdv, bd, cb);
    k_prep<<<1792, 256, 0, stream>>>(Wq,Wk,Wv,Wdk,Wdv,Wd, ln_g, WqT,WkT,WvT,WdkT,WdvT,WdT);
    k_qkv2<<<625, 256, 0, stream>>>(s_j, ln_g, cb, WqT, WkT, WvT, q, kk, vv);
    k_edge<<<15625, 256, 0, stream>>>(r_ij, ln_g, nb32, q, kk, vv, v_j,
                                      WdkT, WdvT, cb, WdT,
                                      acc, acc + 1280000);
    k_out<<<20000, 256, 0, stream>>>(acc, (float*)d_out);
}